// Round 2
// baseline (487.341 us; speedup 1.0000x reference)
//
#include <hip/hip_runtime.h>

// OU scan: x_s = c_s * x_{s-1} + sqrt(1-c_s^2) * z_s,  c_s = exp(-theta*dt_s)
// B=64, S=4096, D=256. float32. 2-pass chunked scan, traffic-optimized:
//  - z is 268 MB vs 256 MB L3: rows 0..7 of every 64-row chunk are loaded
//    NON-TEMPORALLY in both passes, so the cached set (rows 8..63 = 235 MB)
//    fits L3 and pass 2 hits L3 for 87.5% of z instead of thrashing.
//  - pass 2 computes its own chunk carry from the (L2/L3-resident) aggregates,
//    eliminating the separate K2 kernel and its 17 MB of traffic.
//  - 256-thread blocks (4 waves, one chunk each), 8-deep register prefetch.

#define THETA 0.5f
constexpr int Bn = 64;
constexpr int Sn = 4096;
constexpr int Dn = 256;
constexpr int CHUNK = 64;           // rows per chunk
constexpr int NC = Sn / CHUNK;      // 64 chunks per batch
constexpr int WPB = 4;              // chunks (waves) per block
constexpr int NCB = NC / WPB;       // 16 block-columns per batch
constexpr int PF = 8;               // prefetch depth == nt-row count

typedef float f32x4 __attribute__((ext_vector_type(4)));

// ---------------- K1: per-chunk aggregates ----------------
// Wave w of block handles chunk (blk%NCB)*WPB + w of batch blk/NCB.
// Lane owns 4 consecutive d. Rows 0..PF-1 loaded nt (sacrificial set).
__global__ __launch_bounds__(256) void k_agg(
    const float* __restrict__ t,    // [B,S]
    const float* __restrict__ x0,   // [B,D]
    const float* __restrict__ z,    // [B,S,D]
    float* __restrict__ agg)        // [B,NC,D]
{
    const int w    = threadIdx.x >> 6;
    const int lane = threadIdx.x & 63;
    const int b    = blockIdx.x / NCB;
    const int k    = (blockIdx.x % NCB) * WPB + w;
    const int s0   = k * CHUNK;

    __shared__ float2 css[WPB][CHUNK];
    {
        const int r = s0 + lane;
        const float tcur  = t[b * Sn + r];
        const float tprev = (r == 0) ? 0.0f : t[b * Sn + r - 1];
        const float c = __expf(-THETA * (tcur - tprev));
        css[w][lane] = make_float2(c, sqrtf(fmaxf(0.0f, 1.0f - c * c)));
    }
    __syncthreads();

    const int d0 = lane * 4;
    float a0 = 0.f, a1 = 0.f, a2 = 0.f, a3 = 0.f;
    if (k == 0) {
        const f32x4 xv = *(const f32x4*)(x0 + (size_t)b * Dn + d0);
        a0 = xv.x; a1 = xv.y; a2 = xv.z; a3 = xv.w;
    }

    const float* zp = z + ((size_t)b * Sn + s0) * Dn + d0;
    f32x4 buf[PF];   // fully unrolled -> static indices -> VGPRs
#pragma unroll
    for (int i = 0; i < PF; ++i)   // rows 0..7: non-temporal (won't survive anyway)
        buf[i] = __builtin_nontemporal_load((const f32x4*)(zp + (size_t)i * Dn));
#pragma unroll
    for (int r = 0; r < CHUNK; ++r) {
        const f32x4 zv = buf[r & (PF - 1)];
        if (r + PF < CHUNK)        // rows 8..63: normal -> resident in L3 for pass 2
            buf[r & (PF - 1)] = *(const f32x4*)(zp + (size_t)(r + PF) * Dn);
        const float2 cv = css[w][r];        // wave-uniform broadcast, conflict-free
        a0 = fmaf(cv.x, a0, cv.y * zv.x);
        a1 = fmaf(cv.x, a1, cv.y * zv.y);
        a2 = fmaf(cv.x, a2, cv.y * zv.z);
        a3 = fmaf(cv.x, a3, cv.y * zv.w);
    }

    f32x4 av; av.x = a0; av.y = a1; av.z = a2; av.w = a3;
    *(f32x4*)(agg + ((size_t)b * NC + k) * Dn + d0) = av;
}

// ---------------- K2: carry + apply + write output ----------------
// Each wave first scans the chunk aggregates 0..k-1 (L2/L3-resident, 1 KB rows)
// to get its carry-in, then streams its chunk: rows 0..7 nt (not cached),
// rows 8..63 normal (L3 hits from pass 1). Output stores non-temporal.
__global__ __launch_bounds__(256) void k_final(
    const float* __restrict__ t,
    const float* __restrict__ x0,
    const float* __restrict__ z,
    const float* __restrict__ agg,     // [B,NC,D] raw chunk aggregates
    float* __restrict__ out)           // [B,S,D]
{
    const int w    = threadIdx.x >> 6;
    const int lane = threadIdx.x & 63;
    const int b    = blockIdx.x / NCB;
    const int k    = (blockIdx.x % NCB) * WPB + w;
    const int s0   = k * CHUNK;

    __shared__ float2 css[WPB][CHUNK];
    __shared__ float  As[NC];
    {
        const int r = s0 + lane;
        const float tcur  = t[b * Sn + r];
        const float tprev = (r == 0) ? 0.0f : t[b * Sn + r - 1];
        const float c = __expf(-THETA * (tcur - tprev));
        css[w][lane] = make_float2(c, sqrtf(fmaxf(0.0f, 1.0f - c * c)));
    }
    if (threadIdx.x < NC) {   // chunk decay factors A_j, shared by the block's batch
        const int j = threadIdx.x;
        const float tend = t[b * Sn + j * CHUNK + CHUNK - 1];
        const float tpe  = (j == 0) ? 0.0f : t[b * Sn + j * CHUNK - 1];
        As[j] = __expf(-THETA * (tend - tpe));
    }
    __syncthreads();

    const int d0 = lane * 4;
    float a0, a1, a2, a3;
    if (k == 0) {
        const f32x4 xv = *(const f32x4*)(x0 + (size_t)b * Dn + d0);
        a0 = xv.x; a1 = xv.y; a2 = xv.z; a3 = xv.w;
    } else {
        // carry-in = scan of aggregates j=0..k-1 (same fmaf sequence as old K2)
        float c0 = 0.f, c1 = 0.f, c2 = 0.f, c3 = 0.f;
        const float* gp = agg + (size_t)b * NC * Dn + d0;
        int j = 0;
        for (; j + 4 <= k; j += 4) {   // 4 independent loads in flight per group
            const f32x4 g0 = *(const f32x4*)(gp + (size_t)(j + 0) * Dn);
            const f32x4 g1 = *(const f32x4*)(gp + (size_t)(j + 1) * Dn);
            const f32x4 g2 = *(const f32x4*)(gp + (size_t)(j + 2) * Dn);
            const f32x4 g3 = *(const f32x4*)(gp + (size_t)(j + 3) * Dn);
            float A;
            A = As[j + 0]; c0 = fmaf(A, c0, g0.x); c1 = fmaf(A, c1, g0.y); c2 = fmaf(A, c2, g0.z); c3 = fmaf(A, c3, g0.w);
            A = As[j + 1]; c0 = fmaf(A, c0, g1.x); c1 = fmaf(A, c1, g1.y); c2 = fmaf(A, c2, g1.z); c3 = fmaf(A, c3, g1.w);
            A = As[j + 2]; c0 = fmaf(A, c0, g2.x); c1 = fmaf(A, c1, g2.y); c2 = fmaf(A, c2, g2.z); c3 = fmaf(A, c3, g2.w);
            A = As[j + 3]; c0 = fmaf(A, c0, g3.x); c1 = fmaf(A, c1, g3.y); c2 = fmaf(A, c2, g3.z); c3 = fmaf(A, c3, g3.w);
        }
        for (; j < k; ++j) {
            const f32x4 g = *(const f32x4*)(gp + (size_t)j * Dn);
            const float A = As[j];
            c0 = fmaf(A, c0, g.x); c1 = fmaf(A, c1, g.y); c2 = fmaf(A, c2, g.z); c3 = fmaf(A, c3, g.w);
        }
        a0 = c0; a1 = c1; a2 = c2; a3 = c3;
    }

    const float* zp = z + ((size_t)b * Sn + s0) * Dn + d0;
    float* op = out + ((size_t)b * Sn + s0) * Dn + d0;

    f32x4 buf[PF];
#pragma unroll
    for (int i = 0; i < PF; ++i)   // rows 0..7: nt fetch, no allocation/eviction
        buf[i] = __builtin_nontemporal_load((const f32x4*)(zp + (size_t)i * Dn));
#pragma unroll
    for (int r = 0; r < CHUNK; ++r) {
        const f32x4 zv = buf[r & (PF - 1)];
        if (r + PF < CHUNK)        // rows 8..63: normal load -> L3 hit
            buf[r & (PF - 1)] = *(const f32x4*)(zp + (size_t)(r + PF) * Dn);
        const float2 cv = css[w][r];
        a0 = fmaf(cv.x, a0, cv.y * zv.x);
        a1 = fmaf(cv.x, a1, cv.y * zv.y);
        a2 = fmaf(cv.x, a2, cv.y * zv.z);
        a3 = fmaf(cv.x, a3, cv.y * zv.w);
        f32x4 ov; ov.x = a0; ov.y = a1; ov.z = a2; ov.w = a3;
        __builtin_nontemporal_store(ov, (f32x4*)(op + (size_t)r * Dn));
    }
}

extern "C" void kernel_launch(void* const* d_in, const int* in_sizes, int n_in,
                              void* d_out, int out_size, void* d_ws, size_t ws_size,
                              hipStream_t stream) {
    const float* t  = (const float*)d_in[0];   // [B,S,1] f32
    const float* x0 = (const float*)d_in[1];   // [B,1,D] f32
    const float* z  = (const float*)d_in[2];   // [B,S,D] f32
    float* out = (float*)d_out;                // [B,S,D] f32

    float* agg = (float*)d_ws;   // [B,NC,D] = 4 MB chunk aggregates

    k_agg  <<<Bn * NCB, 256, 0, stream>>>(t, x0, z, agg);
    k_final<<<Bn * NCB, 256, 0, stream>>>(t, x0, z, agg, out);
}